// Round 7
// baseline (805.272 us; speedup 1.0000x reference)
//
#include <hip/hip_runtime.h>

typedef __attribute__((ext_vector_type(4))) float f32x4;
typedef __attribute__((ext_vector_type(8))) short bf16x8;

#define BATCH 8
#define MDIM 4096
#define KDIM 4096
#define NDIM 128
#define NT 32      // K tiles of 128
#define NQ 128     // 32-row strips per batch (4096/32)

__device__ __forceinline__ ushort f2bf(float f) {
  unsigned u = __float_as_uint(f);
  unsigned r = (u + 0x7fffu + ((u >> 16) & 1u)) >> 16;  // RNE
  return (ushort)r;
}
__device__ __forceinline__ unsigned au(float f) { return __float_as_uint(f); }

// ---------------- kernel 0: B [b][k][n] fp32 -> Bt [b][n][k] bf16 ----------------
__global__ __launch_bounds__(256) void conv_b(const float* __restrict__ b,
                                              ushort* __restrict__ bt) {
  int t = blockIdx.x * 256 + threadIdx.x;
  int n  = t & (NDIM - 1);
  int k8 = (t >> 7) & 511;
  int bb = t >> 16;
  int k = k8 * 8;
  const float* src = b + ((size_t)bb * KDIM + k) * NDIM + n;
  ushort r[8];
#pragma unroll
  for (int j = 0; j < 8; ++j) r[j] = f2bf(src[(size_t)j * NDIM]);
  ushort* dst = bt + ((size_t)bb * NDIM + n) * KDIM + k;
  *reinterpret_cast<uint4*>(dst) = *reinterpret_cast<const uint4*>(r);
}

// ---------------- kernel 1: pure-read contiguous A scan -> 32-row-granular flags ----
// Block blk streams rows [blk*32, blk*32+32) of the flattened [BATCH*MDIM][KDIM] A
// (512 KB contiguous). Thread t's float4 index within the chunk: t + i*256.
// col4 = (t + (i&3)*256), kt = col4>>5 = (t>>5) + (i&3)*8  -> 4 OR-accumulators.
__global__ __launch_bounds__(256) void scan_a(const float* __restrict__ a,
                                              int* __restrict__ flagsQ) {
  const int t = threadIdx.x;
  const f32x4* p = reinterpret_cast<const f32x4*>(a) + (size_t)blockIdx.x * 32768 + t;
  unsigned nz0 = 0, nz1 = 0, nz2 = 0, nz3 = 0;
#pragma unroll 4
  for (int r = 0; r < 32; ++r) {
    const f32x4* q = p + r * 1024;
    f32x4 v0 = q[0];
    f32x4 v1 = q[256];
    f32x4 v2 = q[512];
    f32x4 v3 = q[768];
    nz0 |= au(v0[0]) | au(v0[1]) | au(v0[2]) | au(v0[3]);
    nz1 |= au(v1[0]) | au(v1[1]) | au(v1[2]) | au(v1[3]);
    nz2 |= au(v2[0]) | au(v2[1]) | au(v2[2]) | au(v2[3]);
    nz3 |= au(v3[0]) | au(v3[1]) | au(v3[2]) | au(v3[3]);
  }
  nz0 &= 0x7fffffffu; nz1 &= 0x7fffffffu;   // -0.0 counts as zero
  nz2 &= 0x7fffffffu; nz3 &= 0x7fffffffu;
#pragma unroll
  for (int d = 1; d < 32; d <<= 1) {        // OR-reduce over 32-lane groups
    nz0 |= __shfl_xor(nz0, d, 64);
    nz1 |= __shfl_xor(nz1, d, 64);
    nz2 |= __shfl_xor(nz2, d, 64);
    nz3 |= __shfl_xor(nz3, d, 64);
  }
  if ((t & 31) == 0) {
    int g = t >> 5;                         // 0..7
    int* f = flagsQ + blockIdx.x * NT;
    f[g]      = (nz0 != 0);
    f[g + 8]  = (nz1 != 0);
    f[g + 16] = (nz2 != 0);
    f[g + 24] = (nz3 != 0);
  }
}

// ---------------- kernel 2: flag-driven GEMM, A read direct fp32 ----------------
// Block: 32 C-rows x 128 n. 4 waves: wave w -> rows (w&1)*16, n-half w>>1.
__global__ __launch_bounds__(256) void sparse_gemm(
    const float* __restrict__ a, const ushort* __restrict__ bt,
    const int* __restrict__ flagsQ, float* __restrict__ c) {
  const int tid  = threadIdx.x;
  const int lane = tid & 63;
  const int wave = tid >> 6;
  const int bb = blockIdx.x & 7;            // batch -> XCD affinity (Bt L2-pinned)
  const int q  = blockIdx.x >> 3;           // 0..127: 32-row strip
  const int m0 = q * 32 + (wave & 1) * 16;
  const int nh = wave >> 1;                 // n-half 0/1
  const int lr = lane & 15;
  const int lk = lane >> 4;

  const float*  arow = a  + ((size_t)(bb * MDIM) + m0 + lr) * KDIM + lk * 8;
  const ushort* brow = bt + ((size_t)(bb * NDIM) + nh * 64 + lr) * KDIM + lk * 8;

  const int* fl = flagsQ + (bb * NQ + q) * NT;
  int fv = (lane < 32) ? fl[lane] : 0;
  unsigned long long bal = __ballot(fv != 0);
  unsigned mask = __builtin_amdgcn_readfirstlane((unsigned)(bal & 0xffffffffu));

  f32x4 acc[4];
#pragma unroll
  for (int ni = 0; ni < 4; ++ni)
#pragma unroll
    for (int e = 0; e < 4; ++e) acc[ni][e] = 0.f;

  f32x4 raA[8], raB[8];                     // statically-named pair buffers

  auto loadA = [&](f32x4 (&ra)[8], int kt) {
    const float* p = arow + (size_t)kt * 128;
#pragma unroll
    for (int kk = 0; kk < 4; ++kk) {
      ra[kk * 2]     = *reinterpret_cast<const f32x4*>(p + kk * 32);
      ra[kk * 2 + 1] = *reinterpret_cast<const f32x4*>(p + kk * 32 + 4);
    }
  };
  auto doTile = [&](f32x4 (&ra)[8], int kt) {
    bf16x8 af[4];
#pragma unroll
    for (int kk = 0; kk < 4; ++kk) {
      ushort h[8];
#pragma unroll
      for (int e = 0; e < 4; ++e) {
        h[e]     = f2bf(ra[kk * 2][e]);
        h[e + 4] = f2bf(ra[kk * 2 + 1][e]);
      }
      af[kk] = *reinterpret_cast<bf16x8*>(h);
    }
    const ushort* bp = brow + (size_t)kt * 128;
#pragma unroll
    for (int kk = 0; kk < 4; ++kk) {
      bf16x8 bf[4];
#pragma unroll
      for (int ni = 0; ni < 4; ++ni)
        bf[ni] = *reinterpret_cast<const bf16x8*>(bp + (size_t)ni * 16 * KDIM + kk * 32);
#pragma unroll
      for (int ni = 0; ni < 4; ++ni)
        acc[ni] = __builtin_amdgcn_mfma_f32_16x16x32_bf16(af[kk], bf[ni], acc[ni], 0, 0, 0);
    }
  };

  // pair-wise: keep 2 A-tiles in flight so k1's HBM latency hides under k0's work
  while (mask) {
    int k0 = (int)__builtin_ctz(mask); mask &= mask - 1;
    int k1 = -1;
    if (mask) { k1 = (int)__builtin_ctz(mask); mask &= mask - 1; }
    loadA(raA, k0);
    if (k1 >= 0) loadA(raB, k1);
    doTile(raA, k0);
    if (k1 >= 0) doTile(raB, k1);
  }

  // epilogue: C frag mapping col = lane&15, row = (lane>>4)*4 + j  [m89-verified]
  float* crow = c + ((size_t)(bb * MDIM) + m0) * NDIM + nh * 64;
#pragma unroll
  for (int ni = 0; ni < 4; ++ni)
#pragma unroll
    for (int j = 0; j < 4; ++j)
      crow[(size_t)(lk * 4 + j) * NDIM + ni * 16 + lr] = acc[ni][j];
}

extern "C" void kernel_launch(void* const* d_in, const int* in_sizes, int n_in,
                              void* d_out, int out_size, void* d_ws, size_t ws_size,
                              hipStream_t stream) {
  const float* a = (const float*)d_in[0];   // [8][4096][4096] fp32
  const float* b = (const float*)d_in[1];   // [8][4096][128]  fp32
  float* out = (float*)d_out;               // [8][4096][128]  fp32

  // workspace layout
  ushort* bt  = (ushort*)d_ws;                                  // 8.4 MB
  int* flagsQ = (int*)(bt + (size_t)BATCH * NDIM * KDIM);       // 128 KB

  conv_b<<<2048, 256, 0, stream>>>(b, bt);
  scan_a<<<BATCH * NQ, 256, 0, stream>>>(a, flagsQ);
  sparse_gemm<<<BATCH * NQ, 256, 0, stream>>>(a, bt, flagsQ, out);
}